// Round 4
// baseline (200.369 us; speedup 1.0000x reference)
//
#include <hip/hip_runtime.h>
#include <math.h>

#define PI_F 3.14159265358979323846f
#define TWO_PI_F 6.28318530717958647692f
#define RSQ2 0.70710678118654752440f

// counted DS waits: DS ops retire in issue order within a wave, so
// lgkmcnt(8) after issuing 8 younger ops proves all older DS ops are done.
#define LGKM(n) __asm__ volatile("s_waitcnt lgkmcnt(" #n ")" ::: "memory")
// additive swizzle: injective on [0,512), max 574; breaks the 2-bank
// degeneracy of the stage-0 write pattern (8j+i).
#define LADDR(a) ((a) + ((a) >> 3))

__device__ __forceinline__ float2 cadd(float2 a, float2 b){ return make_float2(a.x+b.x, a.y+b.y); }
__device__ __forceinline__ float2 csub(float2 a, float2 b){ return make_float2(a.x-b.x, a.y-b.y); }
__device__ __forceinline__ float2 cmul(float2 a, float2 b){ return make_float2(a.x*b.x - a.y*b.y, a.x*b.y + a.y*b.x); }
__device__ __forceinline__ float2 cw1(float2 a){ return make_float2(RSQ2*(a.x+a.y), RSQ2*(a.y-a.x)); }  // *W8^1
__device__ __forceinline__ float2 cw2(float2 a){ return make_float2(a.y, -a.x); }                        // *(-i)
__device__ __forceinline__ float2 cw3(float2 a){ return make_float2(RSQ2*(a.y-a.x), -RSQ2*(a.x+a.y)); }  // *W8^3

// in-place DIF-8. On return, slot m holds U_{br[m]}, br = {0,4,2,6,1,5,3,7}.
__device__ __forceinline__ void dft8(float2* v){
    float2 a0=cadd(v[0],v[4]), a1=cadd(v[1],v[5]), a2=cadd(v[2],v[6]), a3=cadd(v[3],v[7]);
    float2 b0=csub(v[0],v[4]);
    float2 b1=cw1(csub(v[1],v[5]));
    float2 b2=cw2(csub(v[2],v[6]));
    float2 b3=cw3(csub(v[3],v[7]));
    float2 c0=cadd(a0,a2), c2=csub(a0,a2), c1=cadd(a1,a3), c3=cw2(csub(a1,a3));
    float2 d0=cadd(b0,b2), d2=csub(b0,b2), d1=cadd(b1,b3), d3=cw2(csub(b1,b3));
    v[0]=cadd(c0,c1); v[1]=csub(c0,c1);   // U0, U4
    v[2]=cadd(c2,c3); v[3]=csub(c2,c3);   // U2, U6
    v[4]=cadd(d0,d1); v[5]=csub(d0,d1);   // U1, U5
    v[6]=cadd(d2,d3); v[7]=csub(d2,d3);   // U3, U7
}

// twiddle powers w^1..w^7 via log-depth tree (computed once, reused by both streams)
__device__ __forceinline__ void calc_pows(float2 w, float2* p){
    p[0] = w;
    p[1] = cmul(w, w);          // w^2
    p[2] = cmul(p[1], w);       // w^3
    p[3] = cmul(p[1], p[1]);    // w^4
    p[4] = cmul(p[2], p[1]);    // w^5
    p[5] = cmul(p[2], p[2]);    // w^6
    p[6] = cmul(p[3], p[2]);    // w^7
}

// Stockham radix-8 stage store: address-slot c gets U_c * w^c at base+step*c.
__device__ __forceinline__ void stage_store(float2* wl, const float2* v, const float2* p,
                                            int base, int step){
    constexpr int br[8] = {0,4,2,6,1,5,3,7};
    wl[LADDR(base)] = v[0];
    #pragma unroll
    for (int c = 1; c < 8; ++c) wl[LADDR(base + step*c)] = cmul(v[br[c]], p[c-1]);
}

__device__ __forceinline__ void stage_load(const float2* wl, float2* v, int j){
    #pragma unroll
    for (int i = 0; i < 8; ++i) v[i] = wl[LADDR(j + 64*i)];
}

// ---------------- sector map (matches reference _polar_masks) ----------------
__device__ __forceinline__ int sector_id(int hm, int wm) {
    const float step = 2.0f / 511.0f;
    float y = -1.0f + step * (float)hm;
    float x = -1.0f + step * (float)wm;
    float radius = sqrtf(x * x + y * y);
    float r = radius / sqrtf(2.0f);
    float a = atan2f(y, x);
    a = fmodf(a, PI_F);
    if (a < 0.0f) a += PI_F;

    const float rstep = (0.9f - 0.08f) / 3.0f;
    const float re0 = 0.08f;
    const float re1 = 0.08f + rstep;
    const float re2 = 0.08f + 2.0f * rstep;
    const float re3 = 0.9f;
    int rb;
    if      (r >= re0 && r < re1)  rb = 0;
    else if (r >= re1 && r < re2)  rb = 1;
    else if (r >= re2 && r <= re3) rb = 2;
    else return -1;

    const float astep = PI_F / 8.0f;
    int ab = 7;
    #pragma unroll
    for (int i = 0; i < 7; ++i) {
        float t0 = astep * (float)i;
        float t1 = astep * (float)(i + 1);
        if (a >= t0 && a < t1) { ab = i; break; }
    }
    return rb * 8 + ab;
}

__device__ __forceinline__ float hannf(int i) {
    return 0.5f * (1.0f - __cosf(TWO_PI_F * (float)i / 511.0f));
}

__device__ __forceinline__ float lumaf(const float* b, size_t off){
    return 0.2989f*b[off] + 0.587f*b[off+262144] + 0.114f*b[off+524288];
}

// XCD-affinity block decode: 512 blocks, img = (blk&7)*4 + ((blk>>3)&3),
// sub = blk>>5 in [0,16). All 16 blocks of img land on XCD img>>2 under
// round-robin dispatch, so each image's 1MB buf slab stays in one L2.
__device__ __forceinline__ void decode_blk(int blk, int& img, int& sub){
    img = (blk & 7) * 4 + ((blk >> 3) & 3);
    sub = blk >> 5;
}

// ---------------- kernel 1: luma + window + row FFT (2 FFTs/wave, dual-buffer) ---
// Block = 8 waves (512 thr); each wave FFTs TWO packed row-pairs (A: rows h0,h0+1
// and B: rows h0+2,h0+3) with counted-lgkm software pipelining.
__global__ __launch_bounds__(512, 4) void rowfft_kernel(const float* __restrict__ pred,
                                                        const float* __restrict__ tgt,
                                                        float4* __restrict__ out4,
                                                        unsigned char* __restrict__ mapT,
                                                        unsigned short* __restrict__ cnt_u16,
                                                        float* __restrict__ acc_rep) {
    __shared__ float2 lds[8 * 1152];
    __shared__ float cbins[24];
    int blk = blockIdx.x;                 // [0,512)
    int img, pb;
    decode_blk(blk, img, pb);             // pb in [0,16)
    int t = threadIdx.x;
    int wv = t >> 6, j = t & 63;
    int hpA = pb * 16 + wv * 2;           // row-pair indices [0,256), even
    int hpB = hpA + 1;
    int h0 = 2 * hpA;                     // rows h0..h0+3
    float2* wlA = lds + wv * 1152;
    float2* wlB = wlA + 576;

    if (blk < 24) acc_rep[blk * 512 + t] = 0.0f;   // zero 16*768 replica floats
    if (t < 24) cbins[t] = 0.0f;
    __syncthreads();
    {                                     // folded sector map + per-block counts
        int wm = blk, hm = t;             // one map column per block: 512*512 total
        int s = sector_id(hm, wm);
        mapT[blk * 512 + t] = (unsigned char)(s < 0 ? 255 : s);
        if (s >= 0) atomicAdd(&cbins[s], 1.0f);
    }

    const float* base = (img < 16) ? (pred + (size_t)img * 786432)
                                   : (tgt  + (size_t)(img - 16) * 786432);
    float whA0 = hannf(h0), whA1 = hannf(h0 + 1);
    float whB0 = hannf(h0 + 2), whB1 = hannf(h0 + 3);
    float2 va[8], vb[8];
    #pragma unroll
    for (int i = 0; i < 8; ++i) {
        int w = j + 64 * i;
        float ww = hannf(w);
        size_t off0 = (size_t)h0 * 512 + w;
        float l0 = lumaf(base, off0);
        float l1 = lumaf(base, off0 + 512);
        float l2 = lumaf(base, off0 + 1024);
        float l3 = lumaf(base, off0 + 1536);
        va[i] = make_float2(l0 * (whA0 * ww), l1 * (whA1 * ww));
        vb[i] = make_float2(l2 * (whB0 * ww), l3 * (whB1 * ww));
    }

    float sn, cs;
    __sincosf(-TWO_PI_F * (float)j / 512.0f, &sn, &cs);
    float2 tw0 = make_float2(cs, sn);
    __sincosf(-TWO_PI_F * (float)((j >> 3) << 3) / 512.0f, &sn, &cs);
    float2 tw1 = make_float2(cs, sn);
    float2 pw[7];

    // ---- pipelined 3-stage Stockham radix-8, two independent streams ----
    calc_pows(tw0, pw);
    dft8(va);
    dft8(vb);
    stage_store(wlA, va, pw, 8 * j, 1);
    stage_store(wlB, vb, pw, 8 * j, 1);
    LGKM(8);                              // A writes done
    stage_load(wlA, va, j);
    LGKM(8);                              // B writes done
    stage_load(wlB, vb, j);
    LGKM(8);                              // A reads done (B reads in flight)
    calc_pows(tw1, pw);
    dft8(va);
    stage_store(wlA, va, pw, (j & 7) + 64 * (j >> 3), 8);
    LGKM(8);                              // B reads done (A writes in flight)
    dft8(vb);
    stage_store(wlB, vb, pw, (j & 7) + 64 * (j >> 3), 8);
    LGKM(8);                              // A writes done
    stage_load(wlA, va, j);
    LGKM(8);                              // B writes done
    stage_load(wlB, vb, j);
    LGKM(8);                              // A reads done (B reads in flight)
    dft8(va);
    LGKM(0);                              // B reads done
    dft8(vb);

    constexpr int br[8] = {0,4,2,6,1,5,3,7};
    size_t kbase = (size_t)img * 256;
    int partner = (64 - j) & 63;
    // Hermitian unpack: Z[512-k]: lane 64-j slot 7-c (j>0) / lane 0 slot (8-c)&7 (j==0)
    #pragma unroll
    for (int c = 0; c < 4; ++c) {
        int k = j + 64 * c;
        // stream A
        float2 zk = va[br[c]];
        float mx = __shfl(va[br[7 - c]].x, partner, 64);
        float my = __shfl(va[br[7 - c]].y, partner, 64);
        float2 zs = va[br[(8 - c) & 7]];
        float2 zm = make_float2(j == 0 ? zs.x : mx, j == 0 ? zs.y : my);
        float4 o = make_float4(0.5f*(zk.x+zm.x), 0.5f*(zk.y-zm.y),
                               0.5f*(zk.y+zm.y), 0.5f*(zm.x-zk.x));
        if (k != 0) out4[(kbase + (size_t)k) * 256 + hpA] = o;
        // stream B
        zk = vb[br[c]];
        mx = __shfl(vb[br[7 - c]].x, partner, 64);
        my = __shfl(vb[br[7 - c]].y, partner, 64);
        zs = vb[br[(8 - c) & 7]];
        zm = make_float2(j == 0 ? zs.x : mx, j == 0 ? zs.y : my);
        o = make_float4(0.5f*(zk.x+zm.x), 0.5f*(zk.y-zm.y),
                        0.5f*(zk.y+zm.y), 0.5f*(zm.x-zk.x));
        if (k != 0) out4[(kbase + (size_t)k) * 256 + hpB] = o;
    }
    if (j == 0) {                         // packed real pair: (F_h[0], F_h[256])
        float2 z0 = va[br[0]], z4 = va[br[4]];
        out4[kbase * 256 + hpA] = make_float4(z0.x, z4.x, z0.y, z4.y);
        z0 = vb[br[0]]; z4 = vb[br[4]];
        out4[kbase * 256 + hpB] = make_float4(z0.x, z4.x, z0.y, z4.y);
    }
    __syncthreads();
    if (t < 24) cnt_u16[t * 512 + blk] = (unsigned short)(int)cbins[t];
}

// ---------------- kernel 2: column FFT + log-mag + sector bins ----------------
// Block = 8 waves (512 thr); each wave handles TWO adjacent columns interleaved
// through ONE 576-slot LDS buffer (every wait covered by the other stream's
// dft8). 36864B LDS + launch_bounds(512,6) -> 24 waves/CU ceiling.
__global__ __launch_bounds__(512, 6) void colfft_kernel(const float2* __restrict__ buf,
                                                        const unsigned char* __restrict__ mapT,
                                                        float* __restrict__ acc_rep) {
    __shared__ float2 lds[8 * 576];
    int blk = blockIdx.x;                 // [0,512)
    int img, cg;
    decode_blk(blk, img, cg);             // cg in [0,16)
    int t = threadIdx.x;
    int wv = t >> 6, j = t & 63;
    int pl = cg * 8 + wv;                 // column-pair within img, [0,128)
    int wA = 2 * pl, wB = wA + 1;         // wA even, wB odd in [1,255]
    float2* wl = lds + wv * 576;

    const float2* colA = buf + (size_t)(img * 256 + wA) * 512;
    float2 va[8], vb[8];
    #pragma unroll
    for (int i = 0; i < 8; ++i) va[i] = colA[j + 64 * i];
    #pragma unroll
    for (int i = 0; i < 8; ++i) vb[i] = colA[512 + j + 64 * i];

    // hoisted sector-map loads: latency hides under the FFT
    bool pairw = (wA == 0);
    const unsigned char* mwA1 = mapT + (size_t)(pairw ? 256 : ((wA + 256) & 511)) * 512;
    const unsigned char* mwA2 = mapT + (size_t)(pairw ? 0   : ((256 - wA) & 511)) * 512;
    const unsigned char* mwB1 = mapT + (size_t)((wB + 256) & 511) * 512;
    const unsigned char* mwB2 = mapT + (size_t)((256 - wB) & 511) * 512;
    unsigned char sA1[8], sA2[8], sB1[8], sB2[8];
    #pragma unroll
    for (int c = 0; c < 8; ++c) {
        int hm = j + 64 * ((c + 4) & 7);              // (h+256)&511
        int hm2 = (256 - (j + 64 * c)) & 511;
        sA1[c] = mwA1[hm];
        sA2[c] = pairw ? mwA2[hm] : mwA2[hm2];
        sB1[c] = mwB1[hm];
        sB2[c] = mwB2[hm2];
    }

    float sn, cs;
    __sincosf(-TWO_PI_F * (float)j / 512.0f, &sn, &cs);
    float2 tw0 = make_float2(cs, sn);
    __sincosf(-TWO_PI_F * (float)((j >> 3) << 3) / 512.0f, &sn, &cs);
    float2 tw1 = make_float2(cs, sn);
    float2 pw[7];

    // ---- single-buffer interleave: A and B time-share wl; each LDS wait is
    // covered by the other stream's dft8 (both streams' data verified identical
    // to the dual-buffer schedule: store(tw0 pows)@8j+c -> load@j+64i ->
    // store(tw1 pows)@(j&7)+64(j>>3)+8c -> load -> final dft8). ----
    calc_pows(tw0, pw);
    dft8(va);
    stage_store(wl, va, pw, 8 * j, 1);    // A0 store
    dft8(vb);                             // covers A0 store
    LGKM(0);                              // A0 stored
    stage_load(wl, va, j);                // A0 load
    LGKM(0);                              // A0 loaded; buffer free
    stage_store(wl, vb, pw, 8 * j, 1);    // B0 store (tw0 pows consumed at issue)
    calc_pows(tw1, pw);
    dft8(va);                             // A stage-1 butterfly; covers B0 store
    LGKM(0);                              // B0 stored
    stage_load(wl, vb, j);                // B0 load
    LGKM(0);                              // B0 loaded; buffer free
    stage_store(wl, va, pw, (j & 7) + 64 * (j >> 3), 8);  // A1 store (tw1 pows)
    dft8(vb);                             // B stage-1; covers A1 store
    LGKM(0);                              // A1 stored
    stage_load(wl, va, j);                // A1 load
    LGKM(0);                              // A1 loaded; buffer free
    stage_store(wl, vb, pw, (j & 7) + 64 * (j >> 3), 8);  // B1 store
    dft8(va);                             // A final; covers B1 store
    LGKM(0);                              // B1 stored
    stage_load(wl, vb, j);                // B1 load
    LGKM(0);                              // B1 loaded
    dft8(vb);                             // B final

    float* wb = (float*)wl;               // FFT scratch dead -> 8 replicas x 25 bins
    #pragma unroll
    for (int i = 0; i < 4; ++i) { int ii = j + 64 * i; if (ii < 200) wb[ii] = 0.0f; }
    LGKM(0);

    constexpr int br[8] = {0,4,2,6,1,5,3,7};
    int partner = (64 - j) & 63;
    int rep = (j & 7) * 25;               // 25*r mod 32 distinct for r in [0,8)
    if (pairw) {
        // unpack two real-column FFTs: F0[k]=(Z[k]+conj(Z[-k]))/2,
        // F256[k]=(Z[k]-conj(Z[-k]))/(2i)
        #pragma unroll
        for (int c = 0; c < 8; ++c) {
            float2 zk = va[br[c]];
            float mx = __shfl(va[br[7 - c]].x, partner, 64);
            float my = __shfl(va[br[7 - c]].y, partner, 64);
            float2 zs = va[br[(8 - c) & 7]];
            float2 zm = make_float2(j == 0 ? zs.x : mx, j == 0 ? zs.y : my);
            float f0x = 0.5f*(zk.x+zm.x), f0y = 0.5f*(zk.y-zm.y);
            float f1x = 0.5f*(zk.y+zm.y), f1y = 0.5f*(zm.x-zk.x);
            float mag0 = __logf(1.0f + sqrtf(f0x*f0x + f0y*f0y));   // col w=0
            float mag1 = __logf(1.0f + sqrtf(f1x*f1x + f1y*f1y));   // col w=256
            int s1 = sA1[c]; if (s1 < 24) atomicAdd(&wb[rep + s1], mag0);
            int s2 = sA2[c]; if (s2 < 24) atomicAdd(&wb[rep + s2], mag1);
        }
    } else {
        #pragma unroll
        for (int c = 0; c < 8; ++c) {
            float2 z = va[br[c]];         // wA in [2,254] -> mirror always valid
            float mag = __logf(1.0f + sqrtf(z.x * z.x + z.y * z.y));
            int s1 = sA1[c]; if (s1 < 24) atomicAdd(&wb[rep + s1], mag);
            int s2 = sA2[c]; if (s2 < 24) atomicAdd(&wb[rep + s2], mag);
        }
    }
    #pragma unroll
    for (int c = 0; c < 8; ++c) {         // stream B: wB in [1,255], always mirrored
        float2 z = vb[br[c]];
        float mag = __logf(1.0f + sqrtf(z.x * z.x + z.y * z.y));
        int s1 = sB1[c]; if (s1 < 24) atomicAdd(&wb[rep + s1], mag);
        int s2 = sB2[c]; if (s2 < 24) atomicAdd(&wb[rep + s2], mag);
    }
    LGKM(0);
    if (j < 24) {
        float sum = 0.0f;
        #pragma unroll
        for (int r = 0; r < 8; ++r) sum += wb[r * 25 + j];
        atomicAdd(&acc_rep[(pl & 15) * 768 + img * 24 + j], sum);
    }
}

// ---------------- kernel 3: reduce replicas/partials -> loss ----------------
__global__ __launch_bounds__(256) void final_kernel(const float* __restrict__ acc_rep,
                                                    const unsigned short* __restrict__ cnt_u16,
                                                    const float* __restrict__ rw,
                                                    float* __restrict__ out) {
    __shared__ float accs[768];
    __shared__ float cnts[24];
    __shared__ float ep[384], et[384], red[384];
    int t = threadIdx.x;
    for (int o = t; o < 768; o += 256) {           // sum 16 replicas (coalesced)
        float s = 0.0f;
        #pragma unroll
        for (int r = 0; r < 16; ++r) s += acc_rep[r * 768 + o];
        accs[o] = s;
    }
    if (t < 192) {                                 // counts: 24 sectors x 8 lanes
        int s = t >> 3, g = t & 7;
        const ushort4* p = (const ushort4*)(cnt_u16 + s * 512 + g * 64);
        float sum = 0.0f;
        #pragma unroll
        for (int i = 0; i < 16; ++i) { ushort4 u = p[i]; sum += (float)(u.x + u.y + u.z + u.w); }
        sum += __shfl_down(sum, 4, 8);
        sum += __shfl_down(sum, 2, 8);
        sum += __shfl_down(sum, 1, 8);
        if (g == 0) cnts[s] = sum;
    }
    __syncthreads();
    for (int idx = t; idx < 384; idx += 256) {     // idx = b*24 + s, b in [0,16)
        int b = idx / 24, s = idx - b * 24;
        float cnt = fmaxf(cnts[s], 1e-6f);
        ep[idx] = accs[b * 24 + s] / cnt;
        et[idx] = accs[(16 + b) * 24 + s] / cnt;
    }
    __syncthreads();
    for (int idx = t; idx < 384; idx += 256) {
        int b = idx / 24, s = idx - b * 24, r = s >> 3;
        int gbase = b * 24 + r * 8;
        float sp = 0.0f, st = 0.0f;
        #pragma unroll
        for (int a = 0; a < 8; ++a) { sp += ep[gbase + a]; st += et[gbase + a]; }
        float pe = ep[idx] / fmaxf(sp, 1e-6f);
        float te = et[idx] / fmaxf(st, 1e-6f);
        float d = pe - te;
        red[idx] = sqrtf(d * d + 1e-6f) * rw[r];
    }
    __syncthreads();
    if (t < 128) red[t] += red[t + 128] + red[t + 256];
    __syncthreads();
    if (t < 64) {
        float vv = red[t] + red[t + 64];
        #pragma unroll
        for (int o = 32; o > 0; o >>= 1) vv += __shfl_down(vv, o, 64);
        if (t == 0) out[0] = vv / 384.0f;
    }
}

extern "C" void kernel_launch(void* const* d_in, const int* in_sizes, int n_in,
                              void* d_out, int out_size, void* d_ws, size_t ws_size,
                              hipStream_t stream) {
    const float* pred = (const float*)d_in[0];
    const float* tgt  = (const float*)d_in[1];
    const float* rw   = (const float*)d_in[2];

    char* ws = (char*)d_ws;
    float* acc_rep       = (float*)ws;                     // 16*768 floats = 49152 B
    unsigned short* cnt  = (unsigned short*)(ws + 49152);  // 24*512*2      = 24576 B
    unsigned char* mapT  = (unsigned char*)(ws + 98304);   // 512*512       = 262144 B
    float2* buf          = (float2*)(ws + 360448);         // 32*256*512*8  = 33.55 MB

    rowfft_kernel<<<512, 512, 0, stream>>>(pred, tgt, (float4*)buf, mapT, cnt, acc_rep);
    colfft_kernel<<<512, 512, 0, stream>>>(buf, mapT, acc_rep);
    final_kernel<<<1, 256, 0, stream>>>(acc_rep, cnt, rw, (float*)d_out);
}